// Round 1
// baseline (77.484 us; speedup 1.0000x reference)
//
#include <hip/hip_runtime.h>

#define BLOCK 256
#define CHUNK 256           // n-points staged per block (== BLOCK: one stage load/thread)
#define MPT   4             // m-points per thread: amortize the LDS broadcast 4x
#define LOG2E 1.44269504088896340736f

// v(p_m) = sum_n exp(-|p_m - g_n|^2) * c_n   (SIGMA = 1)
// exp(-|p-g|^2) = exp(-|p|^2) * [exp(-|g|^2)] * exp2(2*log2e * p.g)
//   - exp(-|g|^2) folded into staged controls (once per n per block)
//   - exp(-|p|^2) applied once per m at the end
// Inner loop per n: ONE broadcast ds_read_b128 shared by MPT m-points.
// Rationale: broadcast b128 still moves 16B x 64 lanes = 1 KiB through the
// per-CU LDS return path (~12 cy). At MPT=1 the LDS pipe was the bottleneck
// (~4096 reads x 12 cy ~ 20 us/CU); MPT=4 cuts LDS traffic 4x so VALU/trans
// (~3.4 us) and LDS (~5 us) are near-balanced.
__global__ void __launch_bounds__(BLOCK)
translations_kernel(const float* __restrict__ gd,
                    const float* __restrict__ controls,
                    const float* __restrict__ points,
                    float* __restrict__ out,
                    int N, int M) {
    __shared__ float4 sg[CHUNK];

    const int tid = threadIdx.x;
    const int n0  = blockIdx.y * CHUNK;

    // Stage chunk: (gx, gy, c0*exp(-|g|^2), c1*exp(-|g|^2)); zero-pad OOB so the
    // main loop needs no tail handling (w * 0 == 0).
    {
        const int n = n0 + tid;
        if (n < N) {
            float2 g = ((const float2*)gd)[n];
            float2 c = ((const float2*)controls)[n];
            float  e = __expf(-(g.x * g.x + g.y * g.y));
            sg[tid] = make_float4(g.x, g.y, c.x * e, c.y * e);
        } else {
            sg[tid] = make_float4(0.f, 0.f, 0.f, 0.f);
        }
    }
    __syncthreads();

    // Each thread owns MPT m-points, strided by BLOCK for coalesced loads/stores.
    const int mbase = blockIdx.x * (BLOCK * MPT) + tid;

    float a0[MPT], a1[MPT], px[MPT], py[MPT], acc0[MPT], acc1[MPT];
#pragma unroll
    for (int k = 0; k < MPT; ++k) {
        const int m = mbase + k * BLOCK;
        float2 p = (m < M) ? ((const float2*)points)[m] : make_float2(0.f, 0.f);
        px[k] = p.x;  py[k] = p.y;
        a0[k] = (2.0f * LOG2E) * p.x;
        a1[k] = (2.0f * LOG2E) * p.y;
        acc0[k] = 0.f;  acc1[k] = 0.f;
    }

#pragma unroll 8
    for (int j = 0; j < CHUNK; ++j) {
        float4 g = sg[j];                          // wave-uniform addr -> LDS broadcast
#pragma unroll
        for (int k = 0; k < MPT; ++k) {            // 4 independent chains: ILP hides pipes
            float t = fmaf(a0[k], g.x, a1[k] * g.y);   // 2*log2e * (p . g)
            float w = __builtin_amdgcn_exp2f(t);       // v_exp_f32
            acc0[k] = fmaf(w, g.z, acc0[k]);
            acc1[k] = fmaf(w, g.w, acc1[k]);
        }
    }

#pragma unroll
    for (int k = 0; k < MPT; ++k) {
        const int m = mbase + k * BLOCK;
        if (m < M) {
            const float s = __expf(-(px[k] * px[k] + py[k] * py[k]));
            atomicAdd(&out[2 * m],     acc0[k] * s);
            atomicAdd(&out[2 * m + 1], acc1[k] * s);
        }
    }
}

extern "C" void kernel_launch(void* const* d_in, const int* in_sizes, int n_in,
                              void* d_out, int out_size, void* d_ws, size_t ws_size,
                              hipStream_t stream) {
    const float* gd       = (const float*)d_in[0];  // [N*2]
    const float* controls = (const float*)d_in[1];  // [N*2]
    const float* points   = (const float*)d_in[2];  // [M,2]
    float* out = (float*)d_out;                     // [M,2] fp32

    const int N = in_sizes[0] / 2;
    const int M = in_sizes[2] / 2;

    // d_out is poisoned with 0xAA before every timed launch; atomics need zeros.
    hipMemsetAsync(d_out, 0, (size_t)out_size * sizeof(float), stream);

    dim3 grid((M + BLOCK * MPT - 1) / (BLOCK * MPT), (N + CHUNK - 1) / CHUNK);
    translations_kernel<<<grid, dim3(BLOCK), 0, stream>>>(gd, controls, points, out, N, M);
}

// Round 2
// 77.430 us; speedup vs baseline: 1.0007x; 1.0007x over previous
//
#include <hip/hip_runtime.h>

#define BLOCK 256
#define CHUNK 256           // n-points per block (grid.y split for occupancy)
#define LOG2E 1.44269504088896340736f

// v(p_m) = sum_n exp(-|p_m - g_n|^2) * c_n   (SIGMA = 1)
// exp(-|p-g|^2) = exp2( a0*gx + a1*gy - LOG2E*|g|^2 - LOG2E*|p|^2 )
//   with a0 = 2*LOG2E*px, a1 = 2*LOG2E*py; the -LOG2E*|p|^2 factor applied
//   once per m at the end.
//
// R1 post-mortem: kernel is LATENCY-bound (pipes ~12% busy at 29us wall vs
// 3.4us VALU floor). MPT=4 @ 1 wave/SIMD regressed -> keep 1024 blocks
// (4 waves/SIMD) and instead delete the LDS round-trip: g/c are read with a
// loop-UNIFORM index from __restrict__ global memory -> compiler emits
// s_load (scalar cache broadcast, deep lgkmcnt pipelining). No LDS, no
// __syncthreads, no staging phase. Arrays are 32KB each -> L1/L2 resident.
__global__ void __launch_bounds__(BLOCK)
translations_kernel(const float* __restrict__ gd,
                    const float* __restrict__ controls,
                    const float* __restrict__ points,
                    float* __restrict__ out,
                    int N, int M) {
    const int tid = threadIdx.x;
    const int m   = blockIdx.x * BLOCK + tid;
    const int n0  = blockIdx.y * CHUNK;
    const int jend = min(CHUNK, N - n0);   // uniform; =256 for our shape

    if (m >= M) return;

    const float2 p  = ((const float2*)points)[m];
    const float  a0 = (2.0f * LOG2E) * p.x;
    const float  a1 = (2.0f * LOG2E) * p.y;

    // 2 n-points per float4; n0 is a multiple of 256 -> 16B aligned.
    const float4* gbase = (const float4*)(gd + 2 * n0);
    const float4* cbase = (const float4*)(controls + 2 * n0);

    float acc0 = 0.f, acc1 = 0.f;
    const int jpairs = jend >> 1;
#pragma unroll 4
    for (int j = 0; j < jpairs; ++j) {
        float4 g = gbase[j];            // uniform addr -> s_load broadcast
        float4 c = cbase[j];
        // n = 2j
        float b0 = fmaf(g.y, g.y, g.x * g.x);          // |g|^2
        float t0 = fmaf(a0, g.x, a1 * g.y);            // 2*log2e*(p.g)
        float w0 = __builtin_amdgcn_exp2f(fmaf(-LOG2E, b0, t0));
        acc0 = fmaf(w0, c.x, acc0);
        acc1 = fmaf(w0, c.y, acc1);
        // n = 2j+1
        float b1 = fmaf(g.w, g.w, g.z * g.z);
        float t1 = fmaf(a0, g.z, a1 * g.w);
        float w1 = __builtin_amdgcn_exp2f(fmaf(-LOG2E, b1, t1));
        acc0 = fmaf(w1, c.z, acc0);
        acc1 = fmaf(w1, c.w, acc1);
    }
    if (jend & 1) {                      // generality; not hit at N=4096
        const int n = jend - 1;
        float2 g = ((const float2*)(gd + 2 * n0))[n];
        float2 c = ((const float2*)(controls + 2 * n0))[n];
        float b = fmaf(g.y, g.y, g.x * g.x);
        float t = fmaf(a0, g.x, a1 * g.y);
        float w = __builtin_amdgcn_exp2f(fmaf(-LOG2E, b, t));
        acc0 = fmaf(w, c.x, acc0);
        acc1 = fmaf(w, c.y, acc1);
    }

    const float s = __builtin_amdgcn_exp2f(-LOG2E * (p.x * p.x + p.y * p.y));
    atomicAdd(&out[2 * m],     acc0 * s);
    atomicAdd(&out[2 * m + 1], acc1 * s);
}

extern "C" void kernel_launch(void* const* d_in, const int* in_sizes, int n_in,
                              void* d_out, int out_size, void* d_ws, size_t ws_size,
                              hipStream_t stream) {
    const float* gd       = (const float*)d_in[0];  // [N*2]
    const float* controls = (const float*)d_in[1];  // [N*2]
    const float* points   = (const float*)d_in[2];  // [M,2]
    float* out = (float*)d_out;                     // [M,2] fp32

    const int N = in_sizes[0] / 2;
    const int M = in_sizes[2] / 2;

    // d_out is poisoned with 0xAA before every timed launch; atomics need zeros.
    hipMemsetAsync(d_out, 0, (size_t)out_size * sizeof(float), stream);

    dim3 grid((M + BLOCK - 1) / BLOCK, (N + CHUNK - 1) / CHUNK);
    translations_kernel<<<grid, dim3(BLOCK), 0, stream>>>(gd, controls, points, out, N, M);
}

// Round 3
// 70.430 us; speedup vs baseline: 1.1002x; 1.0994x over previous
//
#include <hip/hip_runtime.h>

#define BLOCK 256
#define CHUNK 256           // n-points staged per block (== BLOCK: one stage load/thread)
#define LOG2E 1.44269504088896340736f

// v(p_m) = sum_n exp(-|p_m - g_n|^2) * c_n   (SIGMA = 1)
// exp(-|p-g|^2) = exp(-|p|^2) * [exp(-|g|^2)] * exp2(2*log2e * p.g)
//
// R0 (69.2us) beat both MPT=4 (77.5) and scalar-load (77.4) variants: the
// LDS-broadcast inner loop at 4 waves/SIMD is NOT the bottleneck (issue-slot
// floor ~7us vs ~20us kernel residual). Remaining un-varied subsystem: the
// write path — a separate 128KB memset dispatch + 524K fp32 atomic RMWs
// bursting into 2048 L2 lines at kernel tail. This version keeps R0's inner
// loop byte-for-byte and replaces memset+atomics with per-chunk partial
// stores (2MB ws) + a tiny reduce kernel that writes every out element once.
__global__ void __launch_bounds__(BLOCK)
translations_partial(const float* __restrict__ gd,
                     const float* __restrict__ controls,
                     const float* __restrict__ points,
                     float* __restrict__ ws,   // [nchunks][M] float2 partials
                     int N, int M) {
    __shared__ float4 sg[CHUNK];

    const int tid = threadIdx.x;
    const int m   = blockIdx.x * BLOCK + tid;
    const int n0  = blockIdx.y * CHUNK;

    // Stage chunk: (gx, gy, c0*exp(-|g|^2), c1*exp(-|g|^2)); zero-pad OOB so the
    // main loop needs no tail handling (w * 0 == 0).
    {
        const int n = n0 + tid;
        if (n < N) {
            float2 g = ((const float2*)gd)[n];
            float2 c = ((const float2*)controls)[n];
            float  e = __expf(-(g.x * g.x + g.y * g.y));
            sg[tid] = make_float4(g.x, g.y, c.x * e, c.y * e);
        } else {
            sg[tid] = make_float4(0.f, 0.f, 0.f, 0.f);
        }
    }
    __syncthreads();

    if (m >= M) return;

    const float2 p  = ((const float2*)points)[m];
    const float  a0 = (2.0f * LOG2E) * p.x;
    const float  a1 = (2.0f * LOG2E) * p.y;

    float acc0 = 0.f, acc1 = 0.f;
#pragma unroll 8
    for (int j = 0; j < CHUNK; ++j) {
        float4 g = sg[j];                       // wave-uniform addr -> LDS broadcast
        float  t = fmaf(a0, g.x, a1 * g.y);     // 2*log2e * (p . g)
        float  w = __builtin_amdgcn_exp2f(t);   // v_exp_f32
        acc0 = fmaf(w, g.z, acc0);
        acc1 = fmaf(w, g.w, acc1);
    }

    const float s = __expf(-(p.x * p.x + p.y * p.y));
    // Plain coalesced store of this chunk's partial — no atomics, no memset dep.
    ((float2*)ws)[(size_t)blockIdx.y * M + m] = make_float2(acc0 * s, acc1 * s);
}

// Sum nchunks partials per m; writes EVERY out element (overwrites poison).
template <int NC>
__global__ void __launch_bounds__(BLOCK)
translations_reduce(const float* __restrict__ ws, float* __restrict__ out, int M) {
    const int m = blockIdx.x * BLOCK + threadIdx.x;
    if (m >= M) return;
    const float2* w = (const float2*)ws;
    float ax = 0.f, ay = 0.f;
#pragma unroll
    for (int c = 0; c < NC; ++c) {
        float2 v = w[(size_t)c * M + m];        // coalesced: lanes -> consecutive m
        ax += v.x;  ay += v.y;
    }
    ((float2*)out)[m] = make_float2(ax, ay);
}

__global__ void __launch_bounds__(BLOCK)
translations_reduce_dyn(const float* __restrict__ ws, float* __restrict__ out,
                        int M, int nchunks) {
    const int m = blockIdx.x * BLOCK + threadIdx.x;
    if (m >= M) return;
    const float2* w = (const float2*)ws;
    float ax = 0.f, ay = 0.f;
    for (int c = 0; c < nchunks; ++c) {
        float2 v = w[(size_t)c * M + m];
        ax += v.x;  ay += v.y;
    }
    ((float2*)out)[m] = make_float2(ax, ay);
}

// Fallback (ws too small): R0's proven memset+atomic path.
__global__ void __launch_bounds__(BLOCK)
translations_atomic(const float* __restrict__ gd,
                    const float* __restrict__ controls,
                    const float* __restrict__ points,
                    float* __restrict__ out, int N, int M) {
    __shared__ float4 sg[CHUNK];
    const int tid = threadIdx.x;
    const int m   = blockIdx.x * BLOCK + tid;
    const int n0  = blockIdx.y * CHUNK;
    {
        const int n = n0 + tid;
        if (n < N) {
            float2 g = ((const float2*)gd)[n];
            float2 c = ((const float2*)controls)[n];
            float  e = __expf(-(g.x * g.x + g.y * g.y));
            sg[tid] = make_float4(g.x, g.y, c.x * e, c.y * e);
        } else {
            sg[tid] = make_float4(0.f, 0.f, 0.f, 0.f);
        }
    }
    __syncthreads();
    if (m >= M) return;
    const float2 p  = ((const float2*)points)[m];
    const float  a0 = (2.0f * LOG2E) * p.x;
    const float  a1 = (2.0f * LOG2E) * p.y;
    float acc0 = 0.f, acc1 = 0.f;
#pragma unroll 8
    for (int j = 0; j < CHUNK; ++j) {
        float4 g = sg[j];
        float  t = fmaf(a0, g.x, a1 * g.y);
        float  w = __builtin_amdgcn_exp2f(t);
        acc0 = fmaf(w, g.z, acc0);
        acc1 = fmaf(w, g.w, acc1);
    }
    const float s = __expf(-(p.x * p.x + p.y * p.y));
    atomicAdd(&out[2 * m],     acc0 * s);
    atomicAdd(&out[2 * m + 1], acc1 * s);
}

extern "C" void kernel_launch(void* const* d_in, const int* in_sizes, int n_in,
                              void* d_out, int out_size, void* d_ws, size_t ws_size,
                              hipStream_t stream) {
    const float* gd       = (const float*)d_in[0];  // [N*2]
    const float* controls = (const float*)d_in[1];  // [N*2]
    const float* points   = (const float*)d_in[2];  // [M,2]
    float* out = (float*)d_out;                     // [M,2] fp32

    const int N = in_sizes[0] / 2;
    const int M = in_sizes[2] / 2;

    const int nchunks = (N + CHUNK - 1) / CHUNK;    // 16 for N=4096
    const size_t ws_need = (size_t)nchunks * (size_t)M * 2 * sizeof(float);  // 2 MB

    dim3 gridA((M + BLOCK - 1) / BLOCK, nchunks);

    if (ws_size >= ws_need && d_ws != nullptr) {
        float* ws = (float*)d_ws;
        translations_partial<<<gridA, dim3(BLOCK), 0, stream>>>(
            gd, controls, points, ws, N, M);
        dim3 gridB((M + BLOCK - 1) / BLOCK);
        if (nchunks == 16) {
            translations_reduce<16><<<gridB, dim3(BLOCK), 0, stream>>>(ws, out, M);
        } else {
            translations_reduce_dyn<<<gridB, dim3(BLOCK), 0, stream>>>(ws, out, M, nchunks);
        }
    } else {
        // d_out is poisoned with 0xAA before every timed launch; atomics need zeros.
        hipMemsetAsync(d_out, 0, (size_t)out_size * sizeof(float), stream);
        translations_atomic<<<gridA, dim3(BLOCK), 0, stream>>>(gd, controls, points, out, N, M);
    }
}